// Round 3
// baseline (518.883 us; speedup 1.0000x reference)
//
#include <hip/hip_runtime.h>

#define NB 128
#define SSEQ 1024
#define TD 512

typedef _Float16 half8 __attribute__((ext_vector_type(8)));
typedef _Float16 half4 __attribute__((ext_vector_type(4)));
typedef _Float16 half2v __attribute__((ext_vector_type(2)));
typedef float f32x4 __attribute__((ext_vector_type(4)));
typedef float f32x2 __attribute__((ext_vector_type(2)));

// ---------------- generic NT GEMM, fp16 MFMA, fp32 accum, fused dtype convert ----------------
// C[m][n] = sum_k A[m][k]*B[n][k]; 64x64 tile, 4 waves.
// AM: 0 = A fp16, 1 = A fp32 (convert in staging), 2 = A fp32 scaled by 1/aRowScale[row*8+bz]
// BM: 0 = B fp16, 1 = B fp32
// outMode: 0 = fp32 store, 1 = fp16 store, 2 = fp32 store to outF + sp*oSplit (split-K partials)
template<int AM, int BM>
__global__ __launch_bounds__(256) void k_gemm(
    const void* __restrict__ Av, int lda, long aSZ,
    const void* __restrict__ Bv, int ldb, long bSZ,
    const float* __restrict__ bias, const float* __restrict__ aRowScale,
    float scale, int doRelu, int outMode,
    float* __restrict__ outF, _Float16* __restrict__ outH,
    int ldc, int cColOff, int mtiles, int kTiles, long oSplit)
{
  __shared__ _Float16 As[64][72];
  __shared__ _Float16 Bs[64][72];
  int mt = blockIdx.x % mtiles, nt = blockIdx.x / mtiles;
  int sp = blockIdx.y, bz = blockIdx.z;
  int tid = threadIdx.x;
  int r = tid >> 2, kq = (tid & 3) * 16;
  int w = tid >> 6, l = tid & 63;
  long aoff = (long)bz * aSZ + (long)(mt * 64 + r) * lda + (long)sp * kTiles * 64 + kq;
  long boff = (long)bz * bSZ + (long)(nt * 64 + r) * ldb + (long)sp * kTiles * 64 + kq;
  const _Float16* apH = (const _Float16*)Av + aoff;
  const float*    apF = (const float*)Av + aoff;
  const _Float16* bpH = (const _Float16*)Bv + boff;
  const float*    bpF = (const float*)Bv + boff;
  float srA = 1.0f;
  if constexpr (AM == 2) srA = 1.0f / aRowScale[(mt * 64 + r) * 8 + bz];

  half8 pa0, pa1, pb0, pb1;
  f32x4 qa0, qa1, qa2, qa3, qc0, qc1, qc2, qc3;
  if constexpr (AM == 0) { pa0 = *(const half8*)apH; pa1 = *(const half8*)(apH + 8); }
  else { qa0 = *(const f32x4*)apF; qa1 = *(const f32x4*)(apF + 4);
         qa2 = *(const f32x4*)(apF + 8); qa3 = *(const f32x4*)(apF + 12); }
  if constexpr (BM == 0) { pb0 = *(const half8*)bpH; pb1 = *(const half8*)(bpH + 8); }
  else { qc0 = *(const f32x4*)bpF; qc1 = *(const f32x4*)(bpF + 4);
         qc2 = *(const f32x4*)(bpF + 8); qc3 = *(const f32x4*)(bpF + 12); }

  f32x4 acc[4];
  #pragma unroll
  for (int c = 0; c < 4; ++c) acc[c] = (f32x4){0.f, 0.f, 0.f, 0.f};
  int fr = l & 15, fo = (l >> 4) * 8;
  for (int kt = 0; kt < kTiles; ++kt) {
    __syncthreads();
    if constexpr (AM == 0) {
      *(half8*)&As[r][kq] = pa0; *(half8*)&As[r][kq + 8] = pa1;
    } else {
      f32x4 s0 = qa0, s1 = qa1, s2 = qa2, s3 = qa3;
      if constexpr (AM == 2) { s0 *= srA; s1 *= srA; s2 *= srA; s3 *= srA; }
      *(half4*)&As[r][kq + 0]  = __builtin_convertvector(s0, half4);
      *(half4*)&As[r][kq + 4]  = __builtin_convertvector(s1, half4);
      *(half4*)&As[r][kq + 8]  = __builtin_convertvector(s2, half4);
      *(half4*)&As[r][kq + 12] = __builtin_convertvector(s3, half4);
    }
    if constexpr (BM == 0) {
      *(half8*)&Bs[r][kq] = pb0; *(half8*)&Bs[r][kq + 8] = pb1;
    } else {
      *(half4*)&Bs[r][kq + 0]  = __builtin_convertvector(qc0, half4);
      *(half4*)&Bs[r][kq + 4]  = __builtin_convertvector(qc1, half4);
      *(half4*)&Bs[r][kq + 8]  = __builtin_convertvector(qc2, half4);
      *(half4*)&Bs[r][kq + 12] = __builtin_convertvector(qc3, half4);
    }
    __syncthreads();
    if (kt + 1 < kTiles) {
      apH += 64; apF += 64; bpH += 64; bpF += 64;
      if constexpr (AM == 0) { pa0 = *(const half8*)apH; pa1 = *(const half8*)(apH + 8); }
      else { qa0 = *(const f32x4*)apF; qa1 = *(const f32x4*)(apF + 4);
             qa2 = *(const f32x4*)(apF + 8); qa3 = *(const f32x4*)(apF + 12); }
      if constexpr (BM == 0) { pb0 = *(const half8*)bpH; pb1 = *(const half8*)(bpH + 8); }
      else { qc0 = *(const f32x4*)bpF; qc1 = *(const f32x4*)(bpF + 4);
             qc2 = *(const f32x4*)(bpF + 8); qc3 = *(const f32x4*)(bpF + 12); }
    }
    #pragma unroll
    for (int ks = 0; ks < 2; ++ks) {
      half8 af = *(const half8*)&As[16 * w + fr][ks * 32 + fo];
      #pragma unroll
      for (int c = 0; c < 4; ++c) {
        half8 bf = *(const half8*)&Bs[16 * c + fr][ks * 32 + fo];
        acc[c] = __builtin_amdgcn_mfma_f32_16x16x32_f16(af, bf, acc[c], 0, 0, 0);
      }
    }
  }
  int lrow = (l >> 4) * 4, lcol = l & 15;
  #pragma unroll
  for (int c = 0; c < 4; ++c) {
    #pragma unroll
    for (int rr = 0; rr < 4; ++rr) {
      int gm = mt * 64 + 16 * w + lrow + rr;
      int gn = nt * 64 + 16 * c + lcol;
      int ecol = gn + bz * cColOff;
      float vv = acc[c][rr];
      if (bias) vv += bias[ecol];
      vv *= scale;
      if (doRelu) vv = fmaxf(vv, 0.f);
      long oidx = (long)gm * ldc + ecol;
      if (outMode == 0) outF[oidx] = vv;
      else if (outMode == 1) outH[oidx] = (_Float16)vv;
      else outF[oidx + (long)sp * oSplit] = vv;
    }
  }
}

// ---------------- vfeat = relu(sum_splits + b2): output 0 + fp16 copy ----------------
__global__ __launch_bounds__(256) void k_vfeat(
    const float* __restrict__ vacc, const float* __restrict__ b2,
    float* __restrict__ outF, _Float16* __restrict__ vf16)
{
  int i = blockIdx.x * 256 + threadIdx.x;
  float vv = b2[i & 511];
  #pragma unroll
  for (int sp = 0; sp < 16; ++sp) vv += vacc[sp * 65536 + i];
  vv = fmaxf(vv, 0.f);
  outF[i] = vv;
  vf16[i] = (_Float16)vv;
}

// ---------------- qk16[n,h,d] = sum_j q[n,h*64+j]*Wk[h*64+j][d] (h<8; 8..15 zero); qb = q.bk ----
__global__ __launch_bounds__(256) void k_qk(
    const float* __restrict__ qf, const float* __restrict__ Wk,
    const float* __restrict__ bk, _Float16* __restrict__ qk16, float* __restrict__ qb)
{
  int n = blockIdx.x, tid = threadIdx.x;
  __shared__ float qs[512];
  qs[tid] = qf[n * 512 + tid];
  qs[tid + 256] = qf[n * 512 + tid + 256];
  __syncthreads();
  _Float16* qn = qk16 + (long)n * 8192;
  #pragma unroll 1
  for (int h = 0; h < 8; ++h) {
    float a0 = 0.f, a1 = 0.f;
    #pragma unroll 8
    for (int j = 0; j < 64; ++j) {
      float qv = qs[h * 64 + j];
      const float* wr = Wk + (long)(h * 64 + j) * 512;
      a0 = fmaf(qv, wr[tid], a0);
      a1 = fmaf(qv, wr[tid + 256], a1);
    }
    qn[h * 512 + tid] = (_Float16)a0;
    qn[h * 512 + tid + 256] = (_Float16)a1;
  }
  #pragma unroll
  for (int h = 8; h < 16; ++h) {
    qn[h * 512 + tid] = (_Float16)0.f;
    qn[h * 512 + tid + 256] = (_Float16)0.f;
  }
  if (tid < 64) {
    #pragma unroll 1
    for (int h = 0; h < 8; ++h) {
      float pb = qs[h * 64 + tid] * bk[h * 64 + tid];
      #pragma unroll
      for (int m = 1; m < 64; m <<= 1) pb += __shfl_xor(pb, m, 64);
      if (tid == 0) qb[n * 8 + h] = pb;
    }
  }
}

// ---------------- fused streaming attention: one 32-row tile per block ----------------
__global__ __launch_bounds__(256) void k_attn(
    const float* __restrict__ t, const int* __restrict__ tlen,
    const _Float16* __restrict__ qk16, const float* __restrict__ qb,
    float* __restrict__ pu, float* __restrict__ pl)
{
  int n = blockIdx.x >> 5, j = blockIdx.x & 31;
  int len = tlen[n];
  int base = j * 32;
  if (base >= len) return;
  int s1 = base + 32; if (s1 > len) s1 = len;
  int tid = threadIdx.x, wid = tid >> 6, l = tid & 63;

  __shared__ __align__(16) _Float16 ts[32][520];
  __shared__ __align__(16) float ws[32][8];
  __shared__ float lred[8];
  if (tid < 8) lred[tid] = 0.f;

  const float* tn = t + (long)n * SSEQ * TD;
  // ---- stage 32 rows fp32->fp16 into LDS (coalesced, 2-chunk pipeline) ----
  {
    f32x4 a0, a1, b0, b1;
    auto ld = [&](int c, f32x4& x0, f32x4& x1) {
      int sg = base + c * 4 + wid;                // wave-uniform row
      if (sg < s1) {
        const float* p = tn + (long)sg * TD;
        x0 = *(const f32x4*)(p + 4 * l);
        x1 = *(const f32x4*)(p + 256 + 4 * l);
      } else {
        x0 = (f32x4){0.f,0.f,0.f,0.f}; x1 = (f32x4){0.f,0.f,0.f,0.f};
      }
    };
    ld(0, a0, a1); ld(1, b0, b1);
    #pragma unroll
    for (int c = 0; c < 8; c += 2) {
      half4 h0 = __builtin_convertvector(a0, half4);
      half4 h1 = __builtin_convertvector(a1, half4);
      int row = c * 4 + wid;
      if (c + 2 < 8) ld(c + 2, a0, a1);
      *(half4*)&ts[row][4 * l] = h0;
      *(half4*)&ts[row][256 + 4 * l] = h1;
      half4 g0 = __builtin_convertvector(b0, half4);
      half4 g1 = __builtin_convertvector(b1, half4);
      int row2 = c * 4 + 4 + wid;
      if (c + 3 < 8) ld(c + 3, b0, b1);
      *(half4*)&ts[row2][4 * l] = g0;
      *(half4*)&ts[row2][256 + 4 * l] = g1;
    }
  }
  __syncthreads();
  int fr = l & 15, fo = (l >> 4) * 8;
  // ---- scores: waves 0,1 via MFMA; col = head (fr), row = local s ----
  if (wid < 2) {
    const _Float16* qn = qk16 + (long)n * 8192 + fr * 512 + fo;
    f32x4 acc = (f32x4){0.f, 0.f, 0.f, 0.f};
    #pragma unroll 4
    for (int kt = 0; kt < 16; ++kt) {
      half8 bf = *(const half8*)(qn + kt * 32);
      half8 af = *(const half8*)&ts[16 * wid + fr][kt * 32 + fo];
      acc = __builtin_amdgcn_mfma_f32_16x16x32_f16(af, bf, acc, 0, 0, 0);
    }
    float qbr = (fr < 8) ? qb[n * 8 + fr] : 0.f;
    float lac = 0.f;
    #pragma unroll
    for (int r = 0; r < 4; ++r) {
      int sl = 16 * wid + (l >> 4) * 4 + r;
      float wv = 0.f;
      if (fr < 8 && base + sl < s1) wv = __expf(acc[r] + qbr);
      if (fr < 8) ws[sl][fr] = wv;
      lac += wv;
    }
    if (fr < 8) atomicAdd(&lred[fr], lac);
  }
  __syncthreads();
  // ---- PV: all 4 waves, d-split; weights broadcast from LDS ----
  int col0 = 128 * wid + 2 * l;
  f32x2 u[8];
  #pragma unroll
  for (int h = 0; h < 8; ++h) u[h] = (f32x2){0.f, 0.f};
  #pragma unroll 4
  for (int r = 0; r < 32; ++r) {
    f32x4 wa = *(const f32x4*)&ws[r][0];
    f32x4 wb = *(const f32x4*)&ws[r][4];
    half2v tv = *(const half2v*)&ts[r][col0];
    f32x2 tp = { (float)tv[0], (float)tv[1] };
    u[0] += wa[0] * tp; u[1] += wa[1] * tp;
    u[2] += wa[2] * tp; u[3] += wa[3] * tp;
    u[4] += wb[0] * tp; u[5] += wb[1] * tp;
    u[6] += wb[2] * tp; u[7] += wb[3] * tp;
  }
  float* pn = pu + (long)n * 4096;
  #pragma unroll
  for (int h = 0; h < 8; ++h) {
    atomicAdd(&pn[h * 512 + col0], u[h][0]);
    atomicAdd(&pn[h * 512 + col0 + 1], u[h][1]);
  }
  if (tid < 8) atomicAdd(&pl[n * 8 + tid], lred[tid]);  // lred final since pre-PV barrier
}

extern "C" void kernel_launch(void* const* d_in, const int* in_sizes, int n_in,
                              void* d_out, int out_size, void* d_ws, size_t ws_size,
                              hipStream_t stream)
{
  const float* v    = (const float*)d_in[0];
  const float* t    = (const float*)d_in[1];
  const int*   tlen = (const int*)d_in[2];
  const float* W1   = (const float*)d_in[3];
  const float* b1   = (const float*)d_in[4];
  const float* W2   = (const float*)d_in[5];
  const float* b2   = (const float*)d_in[6];
  const float* Wq   = (const float*)d_in[7];
  const float* Wk   = (const float*)d_in[8];
  const float* Wv   = (const float*)d_in[9];
  const float* bq   = (const float*)d_in[10];
  const float* bk   = (const float*)d_in[11];
  const float* bv   = (const float*)d_in[12];
  const float* Wo   = (const float*)d_in[13];
  const float* bo   = (const float*)d_in[14];
  float* out = (float*)d_out;

  // ---- workspace layout: fp16 region then fp32 region ----
  _Float16* hb   = (_Float16*)d_ws;
  _Float16* x16  = hb;                  // 786432   [1536][512]
  _Float16* vf16 = hb + 786432l;        // 65536    [128][512]
  _Float16* ctx16= hb + 851968l;        // 65536    [128][512]
  _Float16* qk16 = hb + 917504l;        // 1048576  [128][16][512]
  float* fb   = (float*)(hb + 1966080l);
  float* vacc = fb;                     // 16*65536 = 1048576
  float* qf   = fb + 1048576l;          // 65536
  float* pu   = fb + 1114112l;          // 524288   [128][8][512]
  float* pl   = fb + 1638400l;          // 1024     [128][8]
  float* qb   = fb + 1639424l;          // 1024

  hipMemsetAsync(pu, 0, (524288l + 1024l) * sizeof(float), stream);
  // fc1: A=v fp32 [1536x768], B=W1 fp32 [512x768] -> relu -> x16 fp16
  k_gemm<1,1><<<dim3(192, 1, 1), 256, 0, stream>>>(v, 768, 0, W1, 768, 0,
      b1, nullptr, 1.f, 1, 1, nullptr, x16, 512, 0, 24, 12, 0);
  // fc2 split-K(16): A=x16 fp16 [128x6144], B=W2 fp32 -> partials vacc[16][65536]
  k_gemm<0,1><<<dim3(16, 16, 1), 256, 0, stream>>>(x16, 6144, 0, W2, 6144, 0,
      nullptr, nullptr, 1.f, 0, 2, vacc, nullptr, 512, 0, 2, 6, 65536);
  k_vfeat<<<256, 256, 0, stream>>>(vacc, b2, out, vf16);
  // q = (vfeat @ Wq^T + bq) * 0.125 -> qf fp32
  k_gemm<0,1><<<dim3(16, 1, 1), 256, 0, stream>>>(vf16, 512, 0, Wq, 512, 0,
      bq, nullptr, 0.125f, 0, 0, qf, nullptr, 512, 0, 2, 8, 0);
  k_qk<<<128, 256, 0, stream>>>(qf, Wk, bk, qk16, qb);
  k_attn<<<NB * 32, 256, 0, stream>>>(t, tlen, qk16, qb, pu, pl);
  // ctx: A = pu fp32 normalized by 1/pl (fused k_norm), B=Wv fp32, batched over heads
  k_gemm<2,1><<<dim3(2, 1, 8), 256, 0, stream>>>(pu, 4096, 512, Wv, 512, 32768,
      bv, pl, 1.f, 0, 1, nullptr, ctx16, 512, 64, 2, 8, 0);
  // attn_out = ctx @ Wo^T + bo -> output 1
  k_gemm<0,1><<<dim3(16, 1, 1), 256, 0, stream>>>(ctx16, 512, 0, Wo, 512, 0,
      bo, nullptr, 1.f, 0, 0, out + 65536, nullptr, 512, 0, 2, 8, 0);
}

// Round 4
// 491.258 us; speedup vs baseline: 1.0562x; 1.0562x over previous
//
#include <hip/hip_runtime.h>

#define NB 128
#define SSEQ 1024
#define TD 512

typedef _Float16 half8 __attribute__((ext_vector_type(8)));
typedef _Float16 half4 __attribute__((ext_vector_type(4)));
typedef float f32x4 __attribute__((ext_vector_type(4)));

// ---------------- generic NT GEMM, fp16 MFMA, fp32 accum, fused dtype convert ----------------
// C[m][n] = sum_k A[m][k]*B[n][k]; 64x64 tile, 4 waves.
// AM: 0 = A fp16, 1 = A fp32 (convert in staging), 2 = A fp32 scaled by 1/aRowScale[row*8+bz]
// BM: 0 = B fp16, 1 = B fp32
// outMode: 0 = fp32 store, 1 = fp16 store, 2 = fp32 store to outF + sp*oSplit (split-K partials)
template<int AM, int BM>
__global__ __launch_bounds__(256) void k_gemm(
    const void* __restrict__ Av, int lda, long aSZ,
    const void* __restrict__ Bv, int ldb, long bSZ,
    const float* __restrict__ bias, const float* __restrict__ aRowScale,
    float scale, int doRelu, int outMode,
    float* __restrict__ outF, _Float16* __restrict__ outH,
    int ldc, int cColOff, int mtiles, int kTiles, long oSplit)
{
  __shared__ _Float16 As[64][72];
  __shared__ _Float16 Bs[64][72];
  int mt = blockIdx.x % mtiles, nt = blockIdx.x / mtiles;
  int sp = blockIdx.y, bz = blockIdx.z;
  int tid = threadIdx.x;
  int r = tid >> 2, kq = (tid & 3) * 16;
  int w = tid >> 6, l = tid & 63;
  long aoff = (long)bz * aSZ + (long)(mt * 64 + r) * lda + (long)sp * kTiles * 64 + kq;
  long boff = (long)bz * bSZ + (long)(nt * 64 + r) * ldb + (long)sp * kTiles * 64 + kq;
  const _Float16* apH = (const _Float16*)Av + aoff;
  const float*    apF = (const float*)Av + aoff;
  const _Float16* bpH = (const _Float16*)Bv + boff;
  const float*    bpF = (const float*)Bv + boff;
  float srA = 1.0f;
  if constexpr (AM == 2) srA = 1.0f / aRowScale[(mt * 64 + r) * 8 + bz];

  half8 pa0, pa1, pb0, pb1;
  f32x4 qa0, qa1, qa2, qa3, qc0, qc1, qc2, qc3;
  if constexpr (AM == 0) { pa0 = *(const half8*)apH; pa1 = *(const half8*)(apH + 8); }
  else { qa0 = *(const f32x4*)apF; qa1 = *(const f32x4*)(apF + 4);
         qa2 = *(const f32x4*)(apF + 8); qa3 = *(const f32x4*)(apF + 12); }
  if constexpr (BM == 0) { pb0 = *(const half8*)bpH; pb1 = *(const half8*)(bpH + 8); }
  else { qc0 = *(const f32x4*)bpF; qc1 = *(const f32x4*)(bpF + 4);
         qc2 = *(const f32x4*)(bpF + 8); qc3 = *(const f32x4*)(bpF + 12); }

  f32x4 acc[4];
  #pragma unroll
  for (int c = 0; c < 4; ++c) acc[c] = (f32x4){0.f, 0.f, 0.f, 0.f};
  int fr = l & 15, fo = (l >> 4) * 8;
  for (int kt = 0; kt < kTiles; ++kt) {
    __syncthreads();
    if constexpr (AM == 0) {
      *(half8*)&As[r][kq] = pa0; *(half8*)&As[r][kq + 8] = pa1;
    } else {
      f32x4 s0 = qa0, s1 = qa1, s2 = qa2, s3 = qa3;
      if constexpr (AM == 2) { s0 *= srA; s1 *= srA; s2 *= srA; s3 *= srA; }
      *(half4*)&As[r][kq + 0]  = __builtin_convertvector(s0, half4);
      *(half4*)&As[r][kq + 4]  = __builtin_convertvector(s1, half4);
      *(half4*)&As[r][kq + 8]  = __builtin_convertvector(s2, half4);
      *(half4*)&As[r][kq + 12] = __builtin_convertvector(s3, half4);
    }
    if constexpr (BM == 0) {
      *(half8*)&Bs[r][kq] = pb0; *(half8*)&Bs[r][kq + 8] = pb1;
    } else {
      *(half4*)&Bs[r][kq + 0]  = __builtin_convertvector(qc0, half4);
      *(half4*)&Bs[r][kq + 4]  = __builtin_convertvector(qc1, half4);
      *(half4*)&Bs[r][kq + 8]  = __builtin_convertvector(qc2, half4);
      *(half4*)&Bs[r][kq + 12] = __builtin_convertvector(qc3, half4);
    }
    __syncthreads();
    if (kt + 1 < kTiles) {
      apH += 64; apF += 64; bpH += 64; bpF += 64;
      if constexpr (AM == 0) { pa0 = *(const half8*)apH; pa1 = *(const half8*)(apH + 8); }
      else { qa0 = *(const f32x4*)apF; qa1 = *(const f32x4*)(apF + 4);
             qa2 = *(const f32x4*)(apF + 8); qa3 = *(const f32x4*)(apF + 12); }
      if constexpr (BM == 0) { pb0 = *(const half8*)bpH; pb1 = *(const half8*)(bpH + 8); }
      else { qc0 = *(const f32x4*)bpF; qc1 = *(const f32x4*)(bpF + 4);
             qc2 = *(const f32x4*)(bpF + 8); qc3 = *(const f32x4*)(bpF + 12); }
    }
    #pragma unroll
    for (int ks = 0; ks < 2; ++ks) {
      half8 af = *(const half8*)&As[16 * w + fr][ks * 32 + fo];
      #pragma unroll
      for (int c = 0; c < 4; ++c) {
        half8 bf = *(const half8*)&Bs[16 * c + fr][ks * 32 + fo];
        acc[c] = __builtin_amdgcn_mfma_f32_16x16x32_f16(af, bf, acc[c], 0, 0, 0);
      }
    }
  }
  int lrow = (l >> 4) * 4, lcol = l & 15;
  #pragma unroll
  for (int c = 0; c < 4; ++c) {
    #pragma unroll
    for (int rr = 0; rr < 4; ++rr) {
      int gm = mt * 64 + 16 * w + lrow + rr;
      int gn = nt * 64 + 16 * c + lcol;
      int ecol = gn + bz * cColOff;
      float vv = acc[c][rr];
      if (bias) vv += bias[ecol];
      vv *= scale;
      if (doRelu) vv = fmaxf(vv, 0.f);
      long oidx = (long)gm * ldc + ecol;
      if (outMode == 0) outF[oidx] = vv;
      else if (outMode == 1) outH[oidx] = (_Float16)vv;
      else outF[oidx + (long)sp * oSplit] = vv;
    }
  }
}

// ---------------- vfeat = relu(sum_splits + b2): output 0 + fp16 copy ----------------
__global__ __launch_bounds__(256) void k_vfeat(
    const float* __restrict__ vacc, const float* __restrict__ b2,
    float* __restrict__ outF, _Float16* __restrict__ vf16)
{
  int i = blockIdx.x * 256 + threadIdx.x;
  float vv = b2[i & 511];
  #pragma unroll
  for (int sp = 0; sp < 16; ++sp) vv += vacc[sp * 65536 + i];
  vv = fmaxf(vv, 0.f);
  outF[i] = vv;
  vf16[i] = (_Float16)vv;
}

// ---------------- qk16[n,h,d] = sum_j q[n,h*64+j]*Wk[h*64+j][d] (h<8; 8..15 zero); qb = q.bk ----
__global__ __launch_bounds__(256) void k_qk(
    const float* __restrict__ qf, const float* __restrict__ Wk,
    const float* __restrict__ bk, _Float16* __restrict__ qk16, float* __restrict__ qb)
{
  int n = blockIdx.x, tid = threadIdx.x;
  __shared__ float qs[512];
  qs[tid] = qf[n * 512 + tid];
  qs[tid + 256] = qf[n * 512 + tid + 256];
  __syncthreads();
  _Float16* qn = qk16 + (long)n * 8192;
  #pragma unroll 1
  for (int h = 0; h < 8; ++h) {
    float a0 = 0.f, a1 = 0.f;
    #pragma unroll 8
    for (int j = 0; j < 64; ++j) {
      float qv = qs[h * 64 + j];
      const float* wr = Wk + (long)(h * 64 + j) * 512;
      a0 = fmaf(qv, wr[tid], a0);
      a1 = fmaf(qv, wr[tid + 256], a1);
    }
    qn[h * 512 + tid] = (_Float16)a0;
    qn[h * 512 + tid + 256] = (_Float16)a1;
  }
  #pragma unroll
  for (int h = 8; h < 16; ++h) {
    qn[h * 512 + tid] = (_Float16)0.f;
    qn[h * 512 + tid + 256] = (_Float16)0.f;
  }
  if (tid < 64) {
    #pragma unroll 1
    for (int h = 0; h < 8; ++h) {
      float pb = qs[h * 64 + tid] * bk[h * 64 + tid];
      #pragma unroll
      for (int m = 1; m < 64; m <<= 1) pb += __shfl_xor(pb, m, 64);
      if (tid == 0) qb[n * 8 + h] = pb;
    }
  }
}

// ---------------- fused streaming attention: 64 rows (2 subtiles) per block, MFMA PV -------
// Scores: D[s][h] = ts·qk16 via MFMA (waves 0,1). Weights -> wst[16][32] fp16 (A-ready).
// PV: O[h][d] = sum_s W[h][s]*T[s][d] via one MFMA per 16-col tile (K=32), acc over subtiles.
__global__ __launch_bounds__(256) void k_attn(
    const float* __restrict__ t, const int* __restrict__ tlen,
    const _Float16* __restrict__ qk16, const float* __restrict__ qb,
    float* __restrict__ pu, float* __restrict__ pl)
{
  int n = blockIdx.x >> 4, j = blockIdx.x & 15;
  int len = tlen[n];
  int base0 = j * 64;
  if (base0 >= len) return;
  int tid = threadIdx.x, wid = tid >> 6, l = tid & 63;
  int fr = l & 15, fo = (l >> 4) * 8;

  __shared__ __align__(16) _Float16 ts[32][520];
  __shared__ __align__(16) _Float16 wst[16][32];
  __shared__ float lred[8];
  if (tid < 8) lred[tid] = 0.f;

  const float* tn = t + (long)n * SSEQ * TD;
  const _Float16* qn = qk16 + (long)n * 8192 + fr * 512 + fo;
  float qbr = (fr < 8) ? qb[n * 8 + fr] : 0.f;

  f32x4 upv[8];
  #pragma unroll
  for (int dt = 0; dt < 8; ++dt) upv[dt] = (f32x4){0.f, 0.f, 0.f, 0.f};

  #pragma unroll 1
  for (int sub = 0; sub < 2; ++sub) {
    int base = base0 + sub * 32;
    if (base >= len) break;                      // block-uniform
    int s1 = base + 32; if (s1 > len) s1 = len;
    __syncthreads();                             // ts/wst reuse guard
    // ---- stage 32 rows fp32->fp16 into LDS (coalesced, 2-chunk pipeline) ----
    {
      f32x4 a0, a1, b0, b1;
      auto ld = [&](int c, f32x4& x0, f32x4& x1) {
        int sg = base + c * 4 + wid;             // wave-uniform row
        if (sg < s1) {
          const float* p = tn + (long)sg * TD;
          x0 = *(const f32x4*)(p + 4 * l);
          x1 = *(const f32x4*)(p + 256 + 4 * l);
        } else {
          x0 = (f32x4){0.f,0.f,0.f,0.f}; x1 = (f32x4){0.f,0.f,0.f,0.f};
        }
      };
      ld(0, a0, a1); ld(1, b0, b1);
      #pragma unroll
      for (int c = 0; c < 8; c += 2) {
        half4 h0 = __builtin_convertvector(a0, half4);
        half4 h1 = __builtin_convertvector(a1, half4);
        int row = c * 4 + wid;
        if (c + 2 < 8) ld(c + 2, a0, a1);
        *(half4*)&ts[row][4 * l] = h0;
        *(half4*)&ts[row][256 + 4 * l] = h1;
        half4 g0 = __builtin_convertvector(b0, half4);
        half4 g1 = __builtin_convertvector(b1, half4);
        int row2 = c * 4 + 4 + wid;
        if (c + 3 < 8) ld(c + 3, b0, b1);
        *(half4*)&ts[row2][4 * l] = g0;
        *(half4*)&ts[row2][256 + 4 * l] = g1;
      }
    }
    __syncthreads();
    // ---- scores: waves 0,1 via MFMA; D col = head (fr), row = local s ----
    if (wid < 2) {
      f32x4 acc = (f32x4){0.f, 0.f, 0.f, 0.f};
      #pragma unroll 4
      for (int kt = 0; kt < 16; ++kt) {
        half8 bf = *(const half8*)(qn + kt * 32);
        half8 af = *(const half8*)&ts[16 * wid + fr][kt * 32 + fo];
        acc = __builtin_amdgcn_mfma_f32_16x16x32_f16(af, bf, acc, 0, 0, 0);
      }
      float lac = 0.f;
      #pragma unroll
      for (int r = 0; r < 4; ++r) {
        int sl = 16 * wid + (l >> 4) * 4 + r;
        float wv = (fr < 8 && base + sl < s1) ? __expf(acc[r] + qbr) : 0.f;
        wst[fr][sl] = (_Float16)wv;              // transposed: A-operand ready
        lac += wv;
      }
      if (fr < 8) atomicAdd(&lred[fr], lac);
    }
    __syncthreads();
    // ---- PV via MFMA: wave owns d-range [128*wid, 128*wid+128), 8 col-tiles ----
    {
      half8 af = *(const half8*)&wst[fr][fo];    // W[head=fr][s=fo..fo+7]
      #pragma unroll
      for (int dt = 0; dt < 8; ++dt) {
        int dcol = 128 * wid + dt * 16 + fr;
        half8 bf;
        #pragma unroll
        for (int jj = 0; jj < 8; ++jj) bf[jj] = ts[fo + jj][dcol];
        upv[dt] = __builtin_amdgcn_mfma_f32_16x16x32_f16(af, bf, upv[dt], 0, 0, 0);
      }
    }
  }
  // ---- epilogue: lane quad q holds heads 4q..4q+3 (valid q<2) at d = 128*wid+dt*16+fr ----
  int quad = l >> 4;
  float* pn = pu + (long)n * 4096;
  if (quad < 2) {
    #pragma unroll
    for (int dt = 0; dt < 8; ++dt) {
      int d = 128 * wid + dt * 16 + fr;
      #pragma unroll
      for (int r = 0; r < 4; ++r)
        atomicAdd(&pn[(quad * 4 + r) * 512 + d], upv[dt][r]);
    }
  }
  if (tid < 8) atomicAdd(&pl[n * 8 + tid], lred[tid]);  // lred final after last PV barrier
}

extern "C" void kernel_launch(void* const* d_in, const int* in_sizes, int n_in,
                              void* d_out, int out_size, void* d_ws, size_t ws_size,
                              hipStream_t stream)
{
  const float* v    = (const float*)d_in[0];
  const float* t    = (const float*)d_in[1];
  const int*   tlen = (const int*)d_in[2];
  const float* W1   = (const float*)d_in[3];
  const float* b1   = (const float*)d_in[4];
  const float* W2   = (const float*)d_in[5];
  const float* b2   = (const float*)d_in[6];
  const float* Wq   = (const float*)d_in[7];
  const float* Wk   = (const float*)d_in[8];
  const float* Wv   = (const float*)d_in[9];
  const float* bq   = (const float*)d_in[10];
  const float* bk   = (const float*)d_in[11];
  const float* bv   = (const float*)d_in[12];
  const float* Wo   = (const float*)d_in[13];
  const float* bo   = (const float*)d_in[14];
  float* out = (float*)d_out;

  // ---- workspace layout: fp16 region then fp32 region ----
  _Float16* hb   = (_Float16*)d_ws;
  _Float16* x16  = hb;                  // 786432   [1536][512]
  _Float16* vf16 = hb + 786432l;        // 65536    [128][512]
  _Float16* ctx16= hb + 851968l;        // 65536    [128][512]
  _Float16* qk16 = hb + 917504l;        // 1048576  [128][16][512]
  float* fb   = (float*)(hb + 1966080l);
  float* vacc = fb;                     // 16*65536 = 1048576
  float* qf   = fb + 1048576l;          // 65536
  float* pu   = fb + 1114112l;          // 524288   [128][8][512]
  float* pl   = fb + 1638400l;          // 1024     [128][8]
  float* qb   = fb + 1639424l;          // 1024

  hipMemsetAsync(pu, 0, (524288l + 1024l) * sizeof(float), stream);
  // fc1: A=v fp32 [1536x768], B=W1 fp32 [512x768] -> relu -> x16 fp16
  k_gemm<1,1><<<dim3(192, 1, 1), 256, 0, stream>>>(v, 768, 0, W1, 768, 0,
      b1, nullptr, 1.f, 1, 1, nullptr, x16, 512, 0, 24, 12, 0);
  // fc2 split-K(16): A=x16 fp16 [128x6144], B=W2 fp32 -> partials vacc[16][65536]
  k_gemm<0,1><<<dim3(16, 16, 1), 256, 0, stream>>>(x16, 6144, 0, W2, 6144, 0,
      nullptr, nullptr, 1.f, 0, 2, vacc, nullptr, 512, 0, 2, 6, 65536);
  k_vfeat<<<256, 256, 0, stream>>>(vacc, b2, out, vf16);
  // q = (vfeat @ Wq^T + bq) * 0.125 -> qf fp32
  k_gemm<0,1><<<dim3(16, 1, 1), 256, 0, stream>>>(vf16, 512, 0, Wq, 512, 0,
      bq, nullptr, 0.125f, 0, 0, qf, nullptr, 512, 0, 2, 8, 0);
  k_qk<<<128, 256, 0, stream>>>(qf, Wk, bk, qk16, qb);
  k_attn<<<NB * 16, 256, 0, stream>>>(t, tlen, qk16, qb, pu, pl);
  // ctx: A = pu fp32 normalized by 1/pl (fused norm), B=Wv fp32, batched over heads
  k_gemm<2,1><<<dim3(2, 1, 8), 256, 0, stream>>>(pu, 4096, 512, Wv, 512, 32768,
      bv, pl, 1.f, 0, 1, nullptr, ctx16, 512, 64, 2, 8, 0);
  // attn_out = ctx @ Wo^T + bo -> output 1
  k_gemm<0,1><<<dim3(16, 1, 1), 256, 0, stream>>>(ctx16, 512, 0, Wo, 512, 0,
      bo, nullptr, 1.f, 0, 0, out + 65536, nullptr, 512, 0, 2, 8, 0);
}

// Round 5
// 464.750 us; speedup vs baseline: 1.1165x; 1.0570x over previous
//
#include <hip/hip_runtime.h>

#define NB 128
#define SSEQ 1024
#define TD 512

typedef _Float16 half8 __attribute__((ext_vector_type(8)));
typedef _Float16 half4 __attribute__((ext_vector_type(4)));
typedef float f32x4 __attribute__((ext_vector_type(4)));

// ---------------- generic NT GEMM, fp16 MFMA, fp32 accum, fused dtype convert ----------------
// C[m][n] = sum_k A[m][k]*B[n][k]; 64x64 tile, 4 waves.
// AM: 0 = A fp16, 1 = A fp32 (convert in staging), 2 = A fp32 scaled by 1/aRowScale[row*8+bz]
// BM: 0 = B fp16, 1 = B fp32
// outMode: 0 = fp32 store, 1 = fp16 store, 2 = fp32 store to outF + sp*oSplit (split-K partials)
template<int AM, int BM>
__global__ __launch_bounds__(256) void k_gemm(
    const void* __restrict__ Av, int lda, long aSZ,
    const void* __restrict__ Bv, int ldb, long bSZ,
    const float* __restrict__ bias, const float* __restrict__ aRowScale,
    float scale, int doRelu, int outMode,
    float* __restrict__ outF, _Float16* __restrict__ outH,
    int ldc, int cColOff, int mtiles, int kTiles, long oSplit)
{
  __shared__ _Float16 As[64][72];
  __shared__ _Float16 Bs[64][72];
  int mt = blockIdx.x % mtiles, nt = blockIdx.x / mtiles;
  int sp = blockIdx.y, bz = blockIdx.z;
  int tid = threadIdx.x;
  int r = tid >> 2, kq = (tid & 3) * 16;
  int w = tid >> 6, l = tid & 63;
  long aoff = (long)bz * aSZ + (long)(mt * 64 + r) * lda + (long)sp * kTiles * 64 + kq;
  long boff = (long)bz * bSZ + (long)(nt * 64 + r) * ldb + (long)sp * kTiles * 64 + kq;
  const _Float16* apH = (const _Float16*)Av + aoff;
  const float*    apF = (const float*)Av + aoff;
  const _Float16* bpH = (const _Float16*)Bv + boff;
  const float*    bpF = (const float*)Bv + boff;
  float srA = 1.0f;
  if constexpr (AM == 2) srA = 1.0f / aRowScale[(mt * 64 + r) * 8 + bz];

  half8 pa0, pa1, pb0, pb1;
  f32x4 qa0, qa1, qa2, qa3, qc0, qc1, qc2, qc3;
  if constexpr (AM == 0) { pa0 = *(const half8*)apH; pa1 = *(const half8*)(apH + 8); }
  else { qa0 = *(const f32x4*)apF; qa1 = *(const f32x4*)(apF + 4);
         qa2 = *(const f32x4*)(apF + 8); qa3 = *(const f32x4*)(apF + 12); }
  if constexpr (BM == 0) { pb0 = *(const half8*)bpH; pb1 = *(const half8*)(bpH + 8); }
  else { qc0 = *(const f32x4*)bpF; qc1 = *(const f32x4*)(bpF + 4);
         qc2 = *(const f32x4*)(bpF + 8); qc3 = *(const f32x4*)(bpF + 12); }

  f32x4 acc[4];
  #pragma unroll
  for (int c = 0; c < 4; ++c) acc[c] = (f32x4){0.f, 0.f, 0.f, 0.f};
  int fr = l & 15, fo = (l >> 4) * 8;
  for (int kt = 0; kt < kTiles; ++kt) {
    __syncthreads();
    if constexpr (AM == 0) {
      *(half8*)&As[r][kq] = pa0; *(half8*)&As[r][kq + 8] = pa1;
    } else {
      f32x4 s0 = qa0, s1 = qa1, s2 = qa2, s3 = qa3;
      if constexpr (AM == 2) { s0 *= srA; s1 *= srA; s2 *= srA; s3 *= srA; }
      *(half4*)&As[r][kq + 0]  = __builtin_convertvector(s0, half4);
      *(half4*)&As[r][kq + 4]  = __builtin_convertvector(s1, half4);
      *(half4*)&As[r][kq + 8]  = __builtin_convertvector(s2, half4);
      *(half4*)&As[r][kq + 12] = __builtin_convertvector(s3, half4);
    }
    if constexpr (BM == 0) {
      *(half8*)&Bs[r][kq] = pb0; *(half8*)&Bs[r][kq + 8] = pb1;
    } else {
      *(half4*)&Bs[r][kq + 0]  = __builtin_convertvector(qc0, half4);
      *(half4*)&Bs[r][kq + 4]  = __builtin_convertvector(qc1, half4);
      *(half4*)&Bs[r][kq + 8]  = __builtin_convertvector(qc2, half4);
      *(half4*)&Bs[r][kq + 12] = __builtin_convertvector(qc3, half4);
    }
    __syncthreads();
    if (kt + 1 < kTiles) {
      apH += 64; apF += 64; bpH += 64; bpF += 64;
      if constexpr (AM == 0) { pa0 = *(const half8*)apH; pa1 = *(const half8*)(apH + 8); }
      else { qa0 = *(const f32x4*)apF; qa1 = *(const f32x4*)(apF + 4);
             qa2 = *(const f32x4*)(apF + 8); qa3 = *(const f32x4*)(apF + 12); }
      if constexpr (BM == 0) { pb0 = *(const half8*)bpH; pb1 = *(const half8*)(bpH + 8); }
      else { qc0 = *(const f32x4*)bpF; qc1 = *(const f32x4*)(bpF + 4);
             qc2 = *(const f32x4*)(bpF + 8); qc3 = *(const f32x4*)(bpF + 12); }
    }
    #pragma unroll
    for (int ks = 0; ks < 2; ++ks) {
      half8 af = *(const half8*)&As[16 * w + fr][ks * 32 + fo];
      #pragma unroll
      for (int c = 0; c < 4; ++c) {
        half8 bf = *(const half8*)&Bs[16 * c + fr][ks * 32 + fo];
        acc[c] = __builtin_amdgcn_mfma_f32_16x16x32_f16(af, bf, acc[c], 0, 0, 0);
      }
    }
  }
  int lrow = (l >> 4) * 4, lcol = l & 15;
  #pragma unroll
  for (int c = 0; c < 4; ++c) {
    #pragma unroll
    for (int rr = 0; rr < 4; ++rr) {
      int gm = mt * 64 + 16 * w + lrow + rr;
      int gn = nt * 64 + 16 * c + lcol;
      int ecol = gn + bz * cColOff;
      float vv = acc[c][rr];
      if (bias) vv += bias[ecol];
      vv *= scale;
      if (doRelu) vv = fmaxf(vv, 0.f);
      long oidx = (long)gm * ldc + ecol;
      if (outMode == 0) outF[oidx] = vv;
      else if (outMode == 1) outH[oidx] = (_Float16)vv;
      else outF[oidx + (long)sp * oSplit] = vv;
    }
  }
}

// ---------------- prep: G16T[h][d][e] = 0.125*sum_j Wq[h64+j][e]*Wk[h64+j][d];
//                  cvec[h][d] = 0.125*sum_j bq[h64+j]*Wk[h64+j][d];
//                  gb[h][e]   = 0.125*sum_j Wq[h64+j][e]*bk[h64+j];
//                  qbc[h]     = 0.125*sum_j bq[h64+j]*bk[h64+j];
//                  + zero pu/pl and qk16 heads 8-15.  grid = 512 (8h x 8et x 8dt)
__global__ __launch_bounds__(256) void k_prep(
    const float* __restrict__ Wq, const float* __restrict__ Wk,
    const float* __restrict__ bq, const float* __restrict__ bk,
    _Float16* __restrict__ G16T, float* __restrict__ gb,
    float* __restrict__ qbc, float* __restrict__ cvec,
    float* __restrict__ pz, _Float16* __restrict__ qz)
{
  int b = blockIdx.x, tid = threadIdx.x;
  int gid = b * 256 + tid;
  // zero pu+pl (525312 floats) and qk16 heads 8-15 (524288 halfs)
  for (long i = gid; i < 131328; i += 131072)
    *(f32x4*)(pz + 4 * i) = (f32x4){0.f, 0.f, 0.f, 0.f};
  {
    long i4 = (long)gid * 4;
    long n = i4 >> 12, off = i4 & 4095;
    *(half4*)(qz + n * 8192 + 4096 + off) = (half4){(_Float16)0, (_Float16)0, (_Float16)0, (_Float16)0};
  }
  int h = b >> 6, et = (b >> 3) & 7, dt = b & 7;
  __shared__ float Aq[64][68];
  __shared__ float Bk[64][68];
  __shared__ float bqs[64], bks[64];
  int r = tid >> 2, cq = (tid & 3) * 16;
  const float* wqp = Wq + (long)(h * 64 + r) * 512 + et * 64 + cq;
  const float* wkp = Wk + (long)(h * 64 + r) * 512 + dt * 64 + cq;
  #pragma unroll
  for (int c = 0; c < 4; ++c) {
    *(f32x4*)&Aq[r][cq + 4 * c] = *(const f32x4*)(wqp + 4 * c);
    *(f32x4*)&Bk[r][cq + 4 * c] = *(const f32x4*)(wkp + 4 * c);
  }
  if (tid < 64) { bqs[tid] = bq[h * 64 + tid]; bks[tid] = bk[h * 64 + tid]; }
  __syncthreads();
  int te = tid & 15, td = tid >> 4;
  float acc[4][4];
  #pragma unroll
  for (int a = 0; a < 4; ++a)
    #pragma unroll
    for (int d = 0; d < 4; ++d) acc[a][d] = 0.f;
  #pragma unroll 4
  for (int j = 0; j < 64; ++j) {
    f32x4 av = *(const f32x4*)&Aq[j][te * 4];
    f32x4 bv = *(const f32x4*)&Bk[j][td * 4];
    #pragma unroll
    for (int a = 0; a < 4; ++a)
      #pragma unroll
      for (int d = 0; d < 4; ++d) acc[a][d] = fmaf(av[a], bv[d], acc[a][d]);
  }
  #pragma unroll
  for (int d = 0; d < 4; ++d) {
    half4 hv = { (_Float16)(0.125f * acc[0][d]), (_Float16)(0.125f * acc[1][d]),
                 (_Float16)(0.125f * acc[2][d]), (_Float16)(0.125f * acc[3][d]) };
    *(half4*)(G16T + (long)h * 262144 + (long)(dt * 64 + td * 4 + d) * 512 + et * 64 + te * 4) = hv;
  }
  if (dt == 0 && td == 0) {
    #pragma unroll
    for (int i = 0; i < 4; ++i) {
      float s = 0.f;
      for (int j = 0; j < 64; ++j) s = fmaf(Aq[j][te * 4 + i], bks[j], s);
      gb[h * 512 + et * 64 + te * 4 + i] = 0.125f * s;
    }
  }
  if (et == 0 && te == 0) {
    #pragma unroll
    for (int i = 0; i < 4; ++i) {
      float s = 0.f;
      for (int j = 0; j < 64; ++j) s = fmaf(Bk[j][td * 4 + i], bqs[j], s);
      cvec[h * 512 + dt * 64 + td * 4 + i] = 0.125f * s;
    }
  }
  if (et == 0 && dt == 0 && tid == 0) {
    float s = 0.f;
    for (int j = 0; j < 64; ++j) s = fmaf(bqs[j], bks[j], s);
    qbc[h] = 0.125f * s;
  }
}

// ---------------- vfeat = relu(sum_splits + b2): output 0 + fp16 copy ----------------
__global__ __launch_bounds__(256) void k_vfeat(
    const float* __restrict__ vacc, const float* __restrict__ b2,
    float* __restrict__ outF, _Float16* __restrict__ vf16)
{
  int i = blockIdx.x * 256 + threadIdx.x;
  float vv = b2[i & 511];
  #pragma unroll
  for (int sp = 0; sp < 16; ++sp) vv += vacc[sp * 65536 + i];
  vv = fmaxf(vv, 0.f);
  outF[i] = vv;
  vf16[i] = (_Float16)vv;
}

// ---------------- qb[n,h] = sum_e vf[n,e]*gb[h,e] + qbc[h] ----------------
__global__ __launch_bounds__(256) void k_qb(
    const _Float16* __restrict__ vf16, const float* __restrict__ gb,
    const float* __restrict__ qbc, float* __restrict__ qb)
{
  int n = blockIdx.x, tid = threadIdx.x;
  __shared__ float qs[512];
  qs[tid] = (float)vf16[n * 512 + tid];
  qs[tid + 256] = (float)vf16[n * 512 + tid + 256];
  __syncthreads();
  int h = tid >> 5, j = tid & 31;
  float p = 0.f;
  for (int e = j; e < 512; e += 32) p = fmaf(qs[e], gb[h * 512 + e], p);
  #pragma unroll
  for (int m = 1; m < 32; m <<= 1) p += __shfl_xor(p, m, 32);
  if (j == 0) qb[n * 8 + h] = p + qbc[h];
}

// ---------------- fused streaming attention: 64 rows (2 subtiles) per block, MFMA PV -------
__global__ __launch_bounds__(256) void k_attn(
    const float* __restrict__ t, const int* __restrict__ tlen,
    const _Float16* __restrict__ qk16, const float* __restrict__ qb,
    float* __restrict__ pu, float* __restrict__ pl)
{
  int n = blockIdx.x >> 4, j = blockIdx.x & 15;
  int len = tlen[n];
  int base0 = j * 64;
  if (base0 >= len) return;
  int tid = threadIdx.x, wid = tid >> 6, l = tid & 63;
  int fr = l & 15, fo = (l >> 4) * 8;

  __shared__ __align__(16) _Float16 ts[32][520];
  __shared__ __align__(16) _Float16 wst[16][32];
  __shared__ float lred[8];
  if (tid < 8) lred[tid] = 0.f;

  const float* tn = t + (long)n * SSEQ * TD;
  const _Float16* qn = qk16 + (long)n * 8192 + fr * 512 + fo;
  float qbr = (fr < 8) ? qb[n * 8 + fr] : 0.f;

  f32x4 upv[8];
  #pragma unroll
  for (int dt = 0; dt < 8; ++dt) upv[dt] = (f32x4){0.f, 0.f, 0.f, 0.f};

  #pragma unroll 1
  for (int sub = 0; sub < 2; ++sub) {
    int base = base0 + sub * 32;
    if (base >= len) break;                      // block-uniform
    int s1 = base + 32; if (s1 > len) s1 = len;
    __syncthreads();                             // ts/wst reuse guard
    // ---- stage 32 rows fp32->fp16 into LDS (coalesced, 2-chunk pipeline) ----
    {
      f32x4 a0, a1, b0, b1;
      auto ld = [&](int c, f32x4& x0, f32x4& x1) {
        int sg = base + c * 4 + wid;             // wave-uniform row
        if (sg < s1) {
          const float* p = tn + (long)sg * TD;
          x0 = *(const f32x4*)(p + 4 * l);
          x1 = *(const f32x4*)(p + 256 + 4 * l);
        } else {
          x0 = (f32x4){0.f,0.f,0.f,0.f}; x1 = (f32x4){0.f,0.f,0.f,0.f};
        }
      };
      ld(0, a0, a1); ld(1, b0, b1);
      #pragma unroll
      for (int c = 0; c < 8; c += 2) {
        half4 h0 = __builtin_convertvector(a0, half4);
        half4 h1 = __builtin_convertvector(a1, half4);
        int row = c * 4 + wid;
        if (c + 2 < 8) ld(c + 2, a0, a1);
        *(half4*)&ts[row][4 * l] = h0;
        *(half4*)&ts[row][256 + 4 * l] = h1;
        half4 g0 = __builtin_convertvector(b0, half4);
        half4 g1 = __builtin_convertvector(b1, half4);
        int row2 = c * 4 + 4 + wid;
        if (c + 3 < 8) ld(c + 3, b0, b1);
        *(half4*)&ts[row2][4 * l] = g0;
        *(half4*)&ts[row2][256 + 4 * l] = g1;
      }
    }
    __syncthreads();
    // ---- scores: waves 0,1 via MFMA; D col = head (fr), row = local s ----
    if (wid < 2) {
      f32x4 acc = (f32x4){0.f, 0.f, 0.f, 0.f};
      #pragma unroll 4
      for (int kt = 0; kt < 16; ++kt) {
        half8 bf = *(const half8*)(qn + kt * 32);
        half8 af = *(const half8*)&ts[16 * wid + fr][kt * 32 + fo];
        acc = __builtin_amdgcn_mfma_f32_16x16x32_f16(af, bf, acc, 0, 0, 0);
      }
      float lac = 0.f;
      #pragma unroll
      for (int r = 0; r < 4; ++r) {
        int sl = 16 * wid + (l >> 4) * 4 + r;
        float wv = (fr < 8 && base + sl < s1) ? __expf(acc[r] + qbr) : 0.f;
        wst[fr][sl] = (_Float16)wv;              // transposed: A-operand ready
        lac += wv;
      }
      if (fr < 8) atomicAdd(&lred[fr], lac);
    }
    __syncthreads();
    // ---- PV via MFMA: wave owns d-range [128*wid, 128*wid+128), 8 col-tiles ----
    {
      half8 af = *(const half8*)&wst[fr][fo];    // W[head=fr][s=fo..fo+7]
      #pragma unroll
      for (int dt = 0; dt < 8; ++dt) {
        int dcol = 128 * wid + dt * 16 + fr;
        half8 bf;
        #pragma unroll
        for (int jj = 0; jj < 8; ++jj) bf[jj] = ts[fo + jj][dcol];
        upv[dt] = __builtin_amdgcn_mfma_f32_16x16x32_f16(af, bf, upv[dt], 0, 0, 0);
      }
    }
  }
  // ---- epilogue: lane quad q holds heads 4q..4q+3 (valid q<2) at d = 128*wid+dt*16+fr ----
  int quad = l >> 4;
  float* pn = pu + (long)n * 4096;
  if (quad < 2) {
    #pragma unroll
    for (int dt = 0; dt < 8; ++dt) {
      int d = 128 * wid + dt * 16 + fr;
      #pragma unroll
      for (int r = 0; r < 4; ++r)
        atomicAdd(&pn[(quad * 4 + r) * 512 + d], upv[dt][r]);
    }
  }
  if (tid < 8) atomicAdd(&pl[n * 8 + tid], lred[tid]);  // lred final after last PV barrier
}

extern "C" void kernel_launch(void* const* d_in, const int* in_sizes, int n_in,
                              void* d_out, int out_size, void* d_ws, size_t ws_size,
                              hipStream_t stream)
{
  const float* v    = (const float*)d_in[0];
  const float* t    = (const float*)d_in[1];
  const int*   tlen = (const int*)d_in[2];
  const float* W1   = (const float*)d_in[3];
  const float* b1   = (const float*)d_in[4];
  const float* W2   = (const float*)d_in[5];
  const float* b2   = (const float*)d_in[6];
  const float* Wq   = (const float*)d_in[7];
  const float* Wk   = (const float*)d_in[8];
  const float* Wv   = (const float*)d_in[9];
  const float* bq   = (const float*)d_in[10];
  const float* bk   = (const float*)d_in[11];
  const float* bv   = (const float*)d_in[12];
  const float* Wo   = (const float*)d_in[13];
  const float* bo   = (const float*)d_in[14];
  float* out = (float*)d_out;

  // ---- workspace layout: fp16 region then fp32 region ----
  _Float16* hb   = (_Float16*)d_ws;
  _Float16* x16  = hb;                  // 786432   [1536][512]
  _Float16* vf16 = hb + 786432l;        // 65536    [128][512]
  _Float16* ctx16= hb + 851968l;        // 65536    [128][512]
  _Float16* qk16 = hb + 917504l;        // 1048576  [128][16][512]
  _Float16* G16T = hb + 1966080l;       // 2097152  [8][512 d][512 e]
  float* fb   = (float*)(hb + 4063232l);
  float* vacc = fb;                     // 16*65536 = 1048576
  float* pu   = fb + 1048576l;          // 524288   [128][8][512]
  float* pl   = fb + 1572864l;          // 1024     [128][8]  (zeroed with pu)
  float* qb   = fb + 1573888l;          // 1024
  float* gb   = fb + 1574912l;          // 4096     [8][512]
  float* qbc  = fb + 1579008l;          // 16
  float* cvec = fb + 1579024l;          // 4096     [8][512]

  // prep: G/gb/cvec/qbc + zero pu/pl + zero qk16 heads 8-15
  k_prep<<<512, 256, 0, stream>>>(Wq, Wk, bq, bk, G16T, gb, qbc, cvec, pu, qk16);
  // fc1: A=v fp32 [1536x768], B=W1 fp32 [512x768] -> relu -> x16 fp16
  k_gemm<1,1><<<dim3(192, 1, 1), 256, 0, stream>>>(v, 768, 0, W1, 768, 0,
      b1, nullptr, 1.f, 1, 1, nullptr, x16, 512, 0, 24, 12, 0);
  // fc2 split-K(16): A=x16 fp16 [128x6144], B=W2 fp32 -> partials vacc[16][65536]
  k_gemm<0,1><<<dim3(16, 16, 1), 256, 0, stream>>>(x16, 6144, 0, W2, 6144, 0,
      nullptr, nullptr, 1.f, 0, 2, vacc, nullptr, 512, 0, 2, 6, 65536);
  k_vfeat<<<256, 256, 0, stream>>>(vacc, b2, out, vf16);
  // qk16[n][h][d] = vf16 @ G16T[h] + cvec[h]  (batched over heads via grid.z, fp16 out)
  k_gemm<0,0><<<dim3(16, 1, 8), 256, 0, stream>>>(vf16, 512, 0, G16T, 512, 262144,
      cvec, nullptr, 1.f, 0, 1, nullptr, qk16, 8192, 512, 2, 8, 0);
  k_qb<<<128, 256, 0, stream>>>(vf16, gb, qbc, qb);
  k_attn<<<NB * 16, 256, 0, stream>>>(t, tlen, qk16, qb, pu, pl);
  // ctx: A = pu fp32 normalized by 1/pl (fused norm), B=Wv fp32, batched over heads
  k_gemm<2,1><<<dim3(2, 1, 8), 256, 0, stream>>>(pu, 4096, 512, Wv, 512, 32768,
      bv, pl, 1.f, 0, 1, nullptr, ctx16, 512, 64, 2, 8, 0);
  // attn_out = ctx @ Wo^T + bo -> output 1
  k_gemm<0,1><<<dim3(16, 1, 1), 256, 0, stream>>>(ctx16, 512, 0, Wo, 512, 0,
      bo, nullptr, 1.f, 0, 0, out + 65536, nullptr, 512, 0, 2, 8, 0);
}

// Round 6
// 464.513 us; speedup vs baseline: 1.1170x; 1.0005x over previous
//
#include <hip/hip_runtime.h>

#define NB 128
#define SSEQ 1024
#define TD 512
#define TSTR 516   // ts row stride (halfs): 258 dw == 2 mod 4 -> PV gather quad-alias 2-way (free)

typedef _Float16 half8 __attribute__((ext_vector_type(8)));
typedef _Float16 half4 __attribute__((ext_vector_type(4)));
typedef float f32x4 __attribute__((ext_vector_type(4)));

// ---------------- shared NT GEMM body, fp16 MFMA, fp32 accum, fused dtype convert ----------------
// C[m][n] = sum_k A[m][k]*B[n][k]; 64x64 tile, 4 waves.
// AM: 0 = A fp16, 1 = A fp32 (convert in staging), 2 = A fp32 scaled by 1/aRowScale[row*8+bz]
// BM: 0 = B fp16, 1 = B fp32
// outMode: 0 = fp32 store, 1 = fp16 store, 2 = fp32 store to outF + sp*oSplit (split-K partials)
template<int AM, int BM>
__device__ __forceinline__ void gemm_body(
    const void* __restrict__ Av, int lda, long aSZ,
    const void* __restrict__ Bv, int ldb, long bSZ,
    const float* __restrict__ bias, const float* __restrict__ aRowScale,
    float scale, int doRelu, int outMode,
    float* __restrict__ outF, _Float16* __restrict__ outH,
    int ldc, int cColOff, int kTiles, long oSplit,
    int mt, int nt, int sp, int bz, int tid)
{
  __shared__ _Float16 As[64][72];
  __shared__ _Float16 Bs[64][72];
  int r = tid >> 2, kq = (tid & 3) * 16;
  int w = tid >> 6, l = tid & 63;
  long aoff = (long)bz * aSZ + (long)(mt * 64 + r) * lda + (long)sp * kTiles * 64 + kq;
  long boff = (long)bz * bSZ + (long)(nt * 64 + r) * ldb + (long)sp * kTiles * 64 + kq;
  const _Float16* apH = (const _Float16*)Av + aoff;
  const float*    apF = (const float*)Av + aoff;
  const _Float16* bpH = (const _Float16*)Bv + boff;
  const float*    bpF = (const float*)Bv + boff;
  float srA = 1.0f;
  if constexpr (AM == 2) srA = 1.0f / aRowScale[(mt * 64 + r) * 8 + bz];

  half8 pa0, pa1, pb0, pb1;
  f32x4 qa0, qa1, qa2, qa3, qc0, qc1, qc2, qc3;
  if constexpr (AM == 0) { pa0 = *(const half8*)apH; pa1 = *(const half8*)(apH + 8); }
  else { qa0 = *(const f32x4*)apF; qa1 = *(const f32x4*)(apF + 4);
         qa2 = *(const f32x4*)(apF + 8); qa3 = *(const f32x4*)(apF + 12); }
  if constexpr (BM == 0) { pb0 = *(const half8*)bpH; pb1 = *(const half8*)(bpH + 8); }
  else { qc0 = *(const f32x4*)bpF; qc1 = *(const f32x4*)(bpF + 4);
         qc2 = *(const f32x4*)(bpF + 8); qc3 = *(const f32x4*)(bpF + 12); }

  f32x4 acc[4];
  #pragma unroll
  for (int c = 0; c < 4; ++c) acc[c] = (f32x4){0.f, 0.f, 0.f, 0.f};
  int fr = l & 15, fo = (l >> 4) * 8;
  for (int kt = 0; kt < kTiles; ++kt) {
    __syncthreads();
    if constexpr (AM == 0) {
      *(half8*)&As[r][kq] = pa0; *(half8*)&As[r][kq + 8] = pa1;
    } else {
      f32x4 s0 = qa0, s1 = qa1, s2 = qa2, s3 = qa3;
      if constexpr (AM == 2) { s0 *= srA; s1 *= srA; s2 *= srA; s3 *= srA; }
      *(half4*)&As[r][kq + 0]  = __builtin_convertvector(s0, half4);
      *(half4*)&As[r][kq + 4]  = __builtin_convertvector(s1, half4);
      *(half4*)&As[r][kq + 8]  = __builtin_convertvector(s2, half4);
      *(half4*)&As[r][kq + 12] = __builtin_convertvector(s3, half4);
    }
    if constexpr (BM == 0) {
      *(half8*)&Bs[r][kq] = pb0; *(half8*)&Bs[r][kq + 8] = pb1;
    } else {
      *(half4*)&Bs[r][kq + 0]  = __builtin_convertvector(qc0, half4);
      *(half4*)&Bs[r][kq + 4]  = __builtin_convertvector(qc1, half4);
      *(half4*)&Bs[r][kq + 8]  = __builtin_convertvector(qc2, half4);
      *(half4*)&Bs[r][kq + 12] = __builtin_convertvector(qc3, half4);
    }
    __syncthreads();
    if (kt + 1 < kTiles) {
      apH += 64; apF += 64; bpH += 64; bpF += 64;
      if constexpr (AM == 0) { pa0 = *(const half8*)apH; pa1 = *(const half8*)(apH + 8); }
      else { qa0 = *(const f32x4*)apF; qa1 = *(const f32x4*)(apF + 4);
             qa2 = *(const f32x4*)(apF + 8); qa3 = *(const f32x4*)(apF + 12); }
      if constexpr (BM == 0) { pb0 = *(const half8*)bpH; pb1 = *(const half8*)(bpH + 8); }
      else { qc0 = *(const f32x4*)bpF; qc1 = *(const f32x4*)(bpF + 4);
             qc2 = *(const f32x4*)(bpF + 8); qc3 = *(const f32x4*)(bpF + 12); }
    }
    #pragma unroll
    for (int ks = 0; ks < 2; ++ks) {
      half8 af = *(const half8*)&As[16 * w + fr][ks * 32 + fo];
      #pragma unroll
      for (int c = 0; c < 4; ++c) {
        half8 bf = *(const half8*)&Bs[16 * c + fr][ks * 32 + fo];
        acc[c] = __builtin_amdgcn_mfma_f32_16x16x32_f16(af, bf, acc[c], 0, 0, 0);
      }
    }
  }
  int lrow = (l >> 4) * 4, lcol = l & 15;
  #pragma unroll
  for (int c = 0; c < 4; ++c) {
    #pragma unroll
    for (int rr = 0; rr < 4; ++rr) {
      int gm = mt * 64 + 16 * w + lrow + rr;
      int gn = nt * 64 + 16 * c + lcol;
      int ecol = gn + bz * cColOff;
      float vv = acc[c][rr];
      if (bias) vv += bias[ecol];
      vv *= scale;
      if (doRelu) vv = fmaxf(vv, 0.f);
      long oidx = (long)gm * ldc + ecol;
      if (outMode == 0) outF[oidx] = vv;
      else if (outMode == 1) outH[oidx] = (_Float16)vv;
      else outF[oidx + (long)sp * oSplit] = vv;
    }
  }
}

template<int AM, int BM>
__global__ __launch_bounds__(256) void k_gemm(
    const void* __restrict__ Av, int lda, long aSZ,
    const void* __restrict__ Bv, int ldb, long bSZ,
    const float* __restrict__ bias, const float* __restrict__ aRowScale,
    float scale, int doRelu, int outMode,
    float* __restrict__ outF, _Float16* __restrict__ outH,
    int ldc, int cColOff, int mtiles, int kTiles, long oSplit)
{
  gemm_body<AM, BM>(Av, lda, aSZ, Bv, ldb, bSZ, bias, aRowScale, scale, doRelu,
                    outMode, outF, outH, ldc, cColOff, kTiles, oSplit,
                    (int)blockIdx.x % mtiles, (int)blockIdx.x / mtiles,
                    (int)blockIdx.y, (int)blockIdx.z, (int)threadIdx.x);
}

// ---------------- prep (blocks 0-511) + fc1 GEMM (blocks 512-703) ----------------
// prep: G16T[h][d][e] = 0.125*Wq_h^T Wk_h (fp16, NT-ready); cvec/gb/qbc bias terms;
//       zeroes pu/pl and qk16 heads 8-15.
__global__ __launch_bounds__(256) void k_prepfc1(
    const float* __restrict__ Wq, const float* __restrict__ Wk,
    const float* __restrict__ bq, const float* __restrict__ bk,
    _Float16* __restrict__ G16T, float* __restrict__ gb,
    float* __restrict__ qbc, float* __restrict__ cvec,
    float* __restrict__ pz, _Float16* __restrict__ qz,
    const float* __restrict__ v, const float* __restrict__ W1,
    const float* __restrict__ b1, _Float16* __restrict__ x16)
{
  int bx = blockIdx.x, tid = threadIdx.x;
  if (bx >= 512) {
    int s = bx - 512;   // 192 blocks: mtiles=24, ntiles=8
    gemm_body<1, 1>(v, 768, 0, W1, 768, 0, b1, nullptr, 1.f, 1, 1,
                    nullptr, x16, 512, 0, 12, 0, s % 24, s / 24, 0, 0, tid);
    return;
  }
  int b = bx;
  int gid = b * 256 + tid;
  for (long i = gid; i < 131328; i += 131072)
    *(f32x4*)(pz + 4 * i) = (f32x4){0.f, 0.f, 0.f, 0.f};
  {
    long i4 = (long)gid * 4;
    long n = i4 >> 12, off = i4 & 4095;
    *(half4*)(qz + n * 8192 + 4096 + off) = (half4){(_Float16)0, (_Float16)0, (_Float16)0, (_Float16)0};
  }
  int h = b >> 6, et = (b >> 3) & 7, dt = b & 7;
  __shared__ float Aq[64][68];
  __shared__ float Bk[64][68];
  __shared__ float bqs[64], bks[64];
  int r = tid >> 2, cq = (tid & 3) * 16;
  const float* wqp = Wq + (long)(h * 64 + r) * 512 + et * 64 + cq;
  const float* wkp = Wk + (long)(h * 64 + r) * 512 + dt * 64 + cq;
  #pragma unroll
  for (int c = 0; c < 4; ++c) {
    *(f32x4*)&Aq[r][cq + 4 * c] = *(const f32x4*)(wqp + 4 * c);
    *(f32x4*)&Bk[r][cq + 4 * c] = *(const f32x4*)(wkp + 4 * c);
  }
  if (tid < 64) { bqs[tid] = bq[h * 64 + tid]; bks[tid] = bk[h * 64 + tid]; }
  __syncthreads();
  int te = tid & 15, td = tid >> 4;
  float acc[4][4];
  #pragma unroll
  for (int a = 0; a < 4; ++a)
    #pragma unroll
    for (int d = 0; d < 4; ++d) acc[a][d] = 0.f;
  #pragma unroll 4
  for (int j = 0; j < 64; ++j) {
    f32x4 av = *(const f32x4*)&Aq[j][te * 4];
    f32x4 bv = *(const f32x4*)&Bk[j][td * 4];
    #pragma unroll
    for (int a = 0; a < 4; ++a)
      #pragma unroll
      for (int d = 0; d < 4; ++d) acc[a][d] = fmaf(av[a], bv[d], acc[a][d]);
  }
  #pragma unroll
  for (int d = 0; d < 4; ++d) {
    half4 hv = { (_Float16)(0.125f * acc[0][d]), (_Float16)(0.125f * acc[1][d]),
                 (_Float16)(0.125f * acc[2][d]), (_Float16)(0.125f * acc[3][d]) };
    *(half4*)(G16T + (long)h * 262144 + (long)(dt * 64 + td * 4 + d) * 512 + et * 64 + te * 4) = hv;
  }
  if (dt == 0 && td == 0) {
    #pragma unroll
    for (int i = 0; i < 4; ++i) {
      float s = 0.f;
      for (int j = 0; j < 64; ++j) s = fmaf(Aq[j][te * 4 + i], bks[j], s);
      gb[h * 512 + et * 64 + te * 4 + i] = 0.125f * s;
    }
  }
  if (et == 0 && te == 0) {
    #pragma unroll
    for (int i = 0; i < 4; ++i) {
      float s = 0.f;
      for (int j = 0; j < 64; ++j) s = fmaf(Bk[j][td * 4 + i], bqs[j], s);
      cvec[h * 512 + dt * 64 + td * 4 + i] = 0.125f * s;
    }
  }
  if (et == 0 && dt == 0 && tid == 0) {
    float s = 0.f;
    for (int j = 0; j < 64; ++j) s = fmaf(bqs[j], bks[j], s);
    qbc[h] = 0.125f * s;
  }
}

// ---------------- vfeat = relu(sum_splits + b2): output 0 + fp16 copy ----------------
__global__ __launch_bounds__(256) void k_vfeat(
    const float* __restrict__ vacc, const float* __restrict__ b2,
    float* __restrict__ outF, _Float16* __restrict__ vf16)
{
  int i = blockIdx.x * 256 + threadIdx.x;
  float vv = b2[i & 511];
  #pragma unroll
  for (int sp = 0; sp < 16; ++sp) vv += vacc[sp * 65536 + i];
  vv = fmaxf(vv, 0.f);
  outF[i] = vv;
  vf16[i] = (_Float16)vv;
}

// ---------------- qk16 GEMM (blocks 0-127) + qb dot (blocks 128-255) ----------------
__global__ __launch_bounds__(256) void k_qkqb(
    const _Float16* __restrict__ vf16, const _Float16* __restrict__ G16T,
    const float* __restrict__ cvec, const float* __restrict__ gb,
    const float* __restrict__ qbc, _Float16* __restrict__ qk16,
    float* __restrict__ qb)
{
  int bx = blockIdx.x, tid = threadIdx.x;
  if (bx < 128) {
    int z = bx >> 4, s = bx & 15;   // mtiles=2, ntiles=8, 8 heads
    gemm_body<0, 0>(vf16, 512, 0, G16T, 512, 262144, cvec, nullptr, 1.f, 0, 1,
                    nullptr, qk16, 8192, 512, 8, 0, s % 2, s / 2, 0, z, tid);
    return;
  }
  int n = bx - 128;
  __shared__ float qs[512];
  qs[tid] = (float)vf16[n * 512 + tid];
  qs[tid + 256] = (float)vf16[n * 512 + tid + 256];
  __syncthreads();
  int h = tid >> 5, j = tid & 31;
  float p = 0.f;
  for (int e = j; e < 512; e += 32) p = fmaf(qs[e], gb[h * 512 + e], p);
  #pragma unroll
  for (int m = 1; m < 32; m <<= 1) p += __shfl_xor(p, m, 32);
  if (j == 0) qb[n * 8 + h] = p + qbc[h];
}

// ---------------- fused streaming attention: one-shot 64-row tile, all-wave MFMA ----------------
// Scores: wave w computes rows 16w..16w+15 (16 MFMA, K=512); weights -> wst[16][72] fp16.
// PV: O[h][d] += W[h][s]*T[s][d], 16 MFMA per wave over K=64. 2 barriers total.
__global__ __launch_bounds__(256) void k_attn(
    const float* __restrict__ t, const int* __restrict__ tlen,
    const _Float16* __restrict__ qk16, const float* __restrict__ qb,
    float* __restrict__ pu, float* __restrict__ pl)
{
  int n = blockIdx.x >> 4, j = blockIdx.x & 15;
  int len = tlen[n];
  int base = j * 64;
  if (base >= len) return;
  int s1 = base + 64; if (s1 > len) s1 = len;
  int tid = threadIdx.x, wid = tid >> 6, l = tid & 63;
  int fr = l & 15, fo = (l >> 4) * 8;

  __shared__ __align__(16) _Float16 ts[64][TSTR];   // 64.5 KB
  __shared__ __align__(16) _Float16 wst[16][72];    // stride 36 dw: A-read conflict-free
  __shared__ float lred[8];
  if (tid < 8) lred[tid] = 0.f;

  const float* tn = t + (long)n * SSEQ * TD;
  // ---- stage 64 rows fp32->fp16 into LDS (coalesced, 2-chunk pipeline) ----
  {
    f32x4 a0, a1, b0, b1;
    auto ld = [&](int c, f32x4& x0, f32x4& x1) {
      int sg = base + c * 4 + wid;               // wave-uniform row
      if (sg < s1) {
        const float* p = tn + (long)sg * TD;
        x0 = *(const f32x4*)(p + 4 * l);
        x1 = *(const f32x4*)(p + 256 + 4 * l);
      } else {
        x0 = (f32x4){0.f,0.f,0.f,0.f}; x1 = (f32x4){0.f,0.f,0.f,0.f};
      }
    };
    ld(0, a0, a1); ld(1, b0, b1);
    #pragma unroll
    for (int c = 0; c < 16; c += 2) {
      half4 h0 = __builtin_convertvector(a0, half4);
      half4 h1 = __builtin_convertvector(a1, half4);
      int row = c * 4 + wid;
      if (c + 2 < 16) ld(c + 2, a0, a1);
      *(half4*)&ts[row][4 * l] = h0;
      *(half4*)&ts[row][256 + 4 * l] = h1;
      half4 g0 = __builtin_convertvector(b0, half4);
      half4 g1 = __builtin_convertvector(b1, half4);
      int row2 = (c + 1) * 4 + wid;
      if (c + 3 < 16) ld(c + 3, b0, b1);
      *(half4*)&ts[row2][4 * l] = g0;
      *(half4*)&ts[row2][256 + 4 * l] = g1;
    }
  }
  __syncthreads();
  // ---- scores: all 4 waves; wave w -> rows 16w..16w+15; D col = head (fr) ----
  {
    const _Float16* qn = qk16 + (long)n * 8192 + fr * 512 + fo;
    f32x4 acc = (f32x4){0.f, 0.f, 0.f, 0.f};
    #pragma unroll 4
    for (int kt = 0; kt < 16; ++kt) {
      half8 bf = *(const half8*)(qn + kt * 32);
      const _Float16* ap = &ts[16 * wid + fr][kt * 32 + fo];
      half4 alo = *(const half4*)ap;             // b64 pair (row stride 8-aligned)
      half4 ahi = *(const half4*)(ap + 4);
      half8 af = { alo[0], alo[1], alo[2], alo[3], ahi[0], ahi[1], ahi[2], ahi[3] };
      acc = __builtin_amdgcn_mfma_f32_16x16x32_f16(af, bf, acc, 0, 0, 0);
    }
    float qbr = (fr < 8) ? qb[n * 8 + fr] : 0.f;
    float lac = 0.f;
    #pragma unroll
    for (int r = 0; r < 4; ++r) {
      int sl = 16 * wid + (l >> 4) * 4 + r;
      float wv = (fr < 8 && base + sl < s1) ? __expf(acc[r] + qbr) : 0.f;
      wst[fr][sl] = (_Float16)wv;
      lac += wv;
    }
    if (fr < 8) atomicAdd(&lred[fr], lac);
  }
  __syncthreads();
  // ---- PV via MFMA: wave owns d-range [128*wid, +128); 8 col-tiles x K=64 ----
  f32x4 upv[8];
  #pragma unroll
  for (int dt = 0; dt < 8; ++dt) upv[dt] = (f32x4){0.f, 0.f, 0.f, 0.f};
  #pragma unroll
  for (int dt = 0; dt < 8; ++dt) {
    int dcol = 128 * wid + dt * 16 + fr;
    #pragma unroll
    for (int ks = 0; ks < 2; ++ks) {
      half8 af = *(const half8*)&wst[fr][ks * 32 + fo];
      half8 bf;
      #pragma unroll
      for (int jj = 0; jj < 8; ++jj) bf[jj] = ts[ks * 32 + fo + jj][dcol];
      upv[dt] = __builtin_amdgcn_mfma_f32_16x16x32_f16(af, bf, upv[dt], 0, 0, 0);
    }
  }
  // ---- epilogue: lane quad q holds heads 4q..4q+3 (valid q<2) ----
  int quad = l >> 4;
  float* pn = pu + (long)n * 4096;
  if (quad < 2) {
    #pragma unroll
    for (int dt = 0; dt < 8; ++dt) {
      int d = 128 * wid + dt * 16 + fr;
      #pragma unroll
      for (int r = 0; r < 4; ++r)
        atomicAdd(&pn[(quad * 4 + r) * 512 + d], upv[dt][r]);
    }
  }
  if (tid < 8) atomicAdd(&pl[n * 8 + tid], lred[tid]);
}

extern "C" void kernel_launch(void* const* d_in, const int* in_sizes, int n_in,
                              void* d_out, int out_size, void* d_ws, size_t ws_size,
                              hipStream_t stream)
{
  const float* v    = (const float*)d_in[0];
  const float* t    = (const float*)d_in[1];
  const int*   tlen = (const int*)d_in[2];
  const float* W1   = (const float*)d_in[3];
  const float* b1   = (const float*)d_in[4];
  const float* W2   = (const float*)d_in[5];
  const float* b2   = (const float*)d_in[6];
  const float* Wq   = (const float*)d_in[7];
  const float* Wk   = (const float*)d_in[8];
  const float* Wv   = (const float*)d_in[9];
  const float* bq   = (const float*)d_in[10];
  const float* bk   = (const float*)d_in[11];
  const float* bv   = (const float*)d_in[12];
  const float* Wo   = (const float*)d_in[13];
  const float* bo   = (const float*)d_in[14];
  float* out = (float*)d_out;

  // ---- workspace layout: fp16 region then fp32 region ----
  _Float16* hb   = (_Float16*)d_ws;
  _Float16* x16  = hb;                  // 786432   [1536][512]
  _Float16* vf16 = hb + 786432l;        // 65536    [128][512]
  _Float16* ctx16= hb + 851968l;        // 65536    [128][512]
  _Float16* qk16 = hb + 917504l;        // 1048576  [128][16][512]
  _Float16* G16T = hb + 1966080l;       // 2097152  [8][512 d][512 e]
  float* fb   = (float*)(hb + 4063232l);
  float* vacc = fb;                     // 16*65536 = 1048576
  float* pu   = fb + 1048576l;          // 524288   [128][8][512]
  float* pl   = fb + 1572864l;          // 1024     [128][8]  (zeroed with pu)
  float* qb   = fb + 1573888l;          // 1024
  float* gb   = fb + 1574912l;          // 4096     [8][512]
  float* qbc  = fb + 1579008l;          // 16
  float* cvec = fb + 1579024l;          // 4096     [8][512]

  // prep (G/gb/cvec/qbc + zero pu/pl/qk16-pad) || fc1 GEMM
  k_prepfc1<<<704, 256, 0, stream>>>(Wq, Wk, bq, bk, G16T, gb, qbc, cvec,
                                     pu, qk16, v, W1, b1, x16);
  // fc2 split-K(16): A=x16 fp16 [128x6144], B=W2 fp32 -> partials vacc[16][65536]
  k_gemm<0,1><<<dim3(16, 16, 1), 256, 0, stream>>>(x16, 6144, 0, W2, 6144, 0,
      nullptr, nullptr, 1.f, 0, 2, vacc, nullptr, 512, 0, 2, 6, 65536);
  k_vfeat<<<256, 256, 0, stream>>>(vacc, b2, out, vf16);
  // qk16 = vf16 @ G16T (+cvec) batched over heads  ||  qb = vf16.gb + qbc
  k_qkqb<<<256, 256, 0, stream>>>(vf16, G16T, cvec, gb, qbc, qk16, qb);
  k_attn<<<NB * 16, 256, 0, stream>>>(t, tlen, qk16, qb, pu, pl);
  // ctx: A = pu fp32 normalized by 1/pl (fused norm), B=Wv fp32, batched over heads
  k_gemm<2,1><<<dim3(2, 1, 8), 256, 0, stream>>>(pu, 4096, 512, Wv, 512, 32768,
      bv, pl, 1.f, 0, 1, nullptr, ctx16, 512, 64, 2, 8, 0);
  // attn_out = ctx @ Wo^T + bo -> output 1
  k_gemm<0,1><<<dim3(16, 1, 1), 256, 0, stream>>>(ctx16, 512, 0, Wo, 512, 0,
      bo, nullptr, 1.f, 0, 0, out + 65536, nullptr, 512, 0, 2, 8, 0);
}